// Round 5
// baseline (3104.998 us; speedup 1.0000x reference)
//
#include <hip/hip_runtime.h>
#include <math.h>

// Dtype flag in module memory: always mapped, never poisoned by the harness.
__device__ int g_is64;

// ---------------------------------------------------------------------------
// Detect edge_index dtype by majority vote over hi-words of the first E
// int64 slots (in bounds for BOTH layouts). int64 data: hi word always 0
// (values < 1M). int32 data: hi word is a random node id, zero w.p. 1e-6.
__global__ void k_detect(const unsigned* __restrict__ w32, long long E) {
    __shared__ int cnt;
    if (threadIdx.x == 0) cnt = 0;
    __syncthreads();
    long long slot = (long long)threadIdx.x * (E / 256);
    if (w32[2 * slot + 1] == 0u) atomicAdd(&cnt, 1);
    __syncthreads();
    if (threadIdx.x == 0) g_is64 = (cnt >= 128) ? 1 : 0;
}

// Load a node index from either view, clamped to [0, n): even a wrong
// interpretation cannot write outside our own buffers.
__device__ __forceinline__ int eload(const int* __restrict__ p32,
                                     const long long* __restrict__ p64,
                                     int is64, long long i, int n) {
    long long v = is64 ? p64[i] : (long long)p32[i];
    int vi = (int)v;
    vi = vi < 0 ? 0 : vi;
    vi = vi >= n ? n - 1 : vi;
    return vi;
}

// ---------------------------------------------------------------------------
// Weighted in-degree (self-loop added later as +1.0)
__global__ void k_deg(const int* __restrict__ ei32, const long long* __restrict__ ei64,
                      long long E, const float* __restrict__ w,
                      float* __restrict__ deg, int n) {
    long long i = (long long)blockIdx.x * 256 + threadIdx.x;
    if (i >= E) return;
    int d = eload(ei32 + E, ei64 + E, g_is64, i, n);
    atomicAdd(&deg[d], w[i]);
}

// dis = 1/sqrt(deg + 1)
__global__ void k_dis(float* __restrict__ deg_dis, int n) {
    int i = blockIdx.x * 256 + threadIdx.x;
    if (i < n) deg_dis[i] = 1.0f / sqrtf(deg_dis[i] + 1.0f);
}

// h-chunk = x @ W1[:, f0:f0+FC]   (LDS-staged, coalesced)
template <int FC>
__global__ void k_proj(const float* __restrict__ x, const float* __restrict__ W1,
                       float* __restrict__ hc, int n, int f0) {
    __shared__ float xs[256 * 25];
    __shared__ float w1s[25 * 16];
    const int base = blockIdx.x * 256;
    const int t = threadIdx.x;
    // FIX (root cause of rounds 1-3): 400 weights, 256 threads -> must stride.
    for (int j = t; j < 400; j += 256) w1s[j] = W1[j];
    for (int j = t; j < 256 * 25; j += 256) {
        long long g = (long long)base * 25 + j;
        xs[j] = (g < (long long)n * 25) ? x[g] : 0.0f;
    }
    __syncthreads();
    const int node = base + t;
    if (node >= n) return;
    float acc[FC];
#pragma unroll
    for (int f = 0; f < FC; ++f) acc[f] = 0.0f;
#pragma unroll
    for (int k = 0; k < 25; ++k) {
        float xv = xs[t * 25 + k];
#pragma unroll
        for (int f = 0; f < FC; ++f) acc[f] += xv * w1s[k * 16 + f0 + f];
    }
#pragma unroll
    for (int f = 0; f < FC; ++f) hc[(long long)node * FC + f] = acc[f];
}

// Layer-1 edge aggregation for one feature chunk: thread = (edge, feature)
template <int FC>
__global__ void k_agg(const int* __restrict__ ei32, const long long* __restrict__ ei64,
                      long long E, const float* __restrict__ w,
                      const float* __restrict__ dis, const float* __restrict__ hc,
                      float* __restrict__ aggc, int n) {
    long long tid = (long long)blockIdx.x * 256 + threadIdx.x;
    if (tid >= E * FC) return;
    long long e = tid / FC;          // FC power of two -> shift
    int f = (int)(tid & (FC - 1));
    int is64 = g_is64;
    int s = eload(ei32, ei64, is64, e, n);
    int d = eload(ei32 + E, ei64 + E, is64, e, n);
    float nrm = dis[s] * w[e] * dis[d];
    atomicAdd(&aggc[(long long)d * FC + f], nrm * hc[(long long)s * FC + f]);
}

// Self-loop + bias + ELU + partial projection with W2 (accumulated over chunks)
template <int FC>
__global__ void k_post(const float* __restrict__ aggc, const float* __restrict__ hc,
                       const float* __restrict__ dis, const float* __restrict__ b1,
                       const float* __restrict__ W2, float* __restrict__ p,
                       int n, int f0, int first) {
    int i = blockIdx.x * 256 + threadIdx.x;
    if (i >= n) return;
    float ds = dis[i];
    float d2 = ds * ds;
    float acc = first ? 0.0f : p[i];
#pragma unroll
    for (int j = 0; j < FC; ++j) {
        float v = aggc[(long long)i * FC + j] + d2 * hc[(long long)i * FC + j] + b1[f0 + j];
        v = (v > 0.0f) ? v : expm1f(v);   // ELU, alpha=1
        acc += v * W2[f0 + j];
    }
    p[i] = acc;
}

// out = b2 + dis^2 * p   (self-loop term; also overwrites harness poison)
__global__ void k_outinit(const float* __restrict__ dis, const float* __restrict__ p,
                          const float* __restrict__ b2, float* __restrict__ out, int n) {
    int i = blockIdx.x * 256 + threadIdx.x;
    if (i < n) {
        float ds = dis[i];
        out[i] = b2[0] + ds * ds * p[i];
    }
}

// Layer-2 edge aggregation (1 feature)
__global__ void k_agg2(const int* __restrict__ ei32, const long long* __restrict__ ei64,
                       long long E, const float* __restrict__ w,
                       const float* __restrict__ dis, const float* __restrict__ p,
                       float* __restrict__ out, int n) {
    long long i = (long long)blockIdx.x * 256 + threadIdx.x;
    if (i >= E) return;
    int is64 = g_is64;
    int s = eload(ei32, ei64, is64, i, n);
    int d = eload(ei32 + E, ei64 + E, is64, i, n);
    atomicAdd(&out[d], dis[s] * w[i] * dis[d] * p[s]);
}

extern "C" void kernel_launch(void* const* d_in, const int* in_sizes, int n_in,
                              void* d_out, int out_size, void* d_ws, size_t ws_size,
                              hipStream_t stream) {
    const float*     x    = (const float*)d_in[0];
    const int*       ei32 = (const int*)d_in[1];
    const long long* ei64 = (const long long*)d_in[1];
    const float*     ew   = (const float*)d_in[2];
    const float*     W1   = (const float*)d_in[3];
    const float*     b1   = (const float*)d_in[4];
    const float*     W2   = (const float*)d_in[5];
    const float*     b2   = (const float*)d_in[6];
    float* out = (float*)d_out;

    const long long n = in_sizes[0] / 25;   // 1,000,000 (x is [n,25] f32)
    const long long E = in_sizes[2];        // 16,000,000 (edge_weight count)

    // ws-size-adaptive layout: dis[n] + p[n] + hc[n*FC] + aggc[n*FC]
    int FC = 16;
    while (FC > 1 && (size_t)(8 * n + 2 * (size_t)FC * 4 * n) > ws_size) FC >>= 1;

    char* ws = (char*)d_ws;
    float* dis = (float*)ws;
    float* p   = (float*)(ws + 4 * n);
    float* hc  = (float*)(ws + 8 * n);
    float* agg = (float*)(ws + 8 * n + (size_t)FC * 4 * n);

    const int gridN = (int)((n + 255) / 256);
    const int gridE = (int)((E + 255) / 256);

    hipMemsetAsync(dis, 0, 4 * n, stream);
    k_detect<<<1, 256, 0, stream>>>((const unsigned*)d_in[1], E);
    k_deg<<<gridE, 256, 0, stream>>>(ei32, ei64, E, ew, dis, (int)n);
    k_dis<<<gridN, 256, 0, stream>>>(dis, (int)n);

#define RUN_CHUNKED(FCV)                                                           \
    for (int f0 = 0; f0 < 16; f0 += FCV) {                                         \
        hipMemsetAsync(agg, 0, (size_t)FCV * 4 * n, stream);                       \
        k_proj<FCV><<<gridN, 256, 0, stream>>>(x, W1, hc, (int)n, f0);             \
        k_agg<FCV><<<(int)((E * FCV + 255) / 256), 256, 0, stream>>>(              \
            ei32, ei64, E, ew, dis, hc, agg, (int)n);                              \
        k_post<FCV><<<gridN, 256, 0, stream>>>(agg, hc, dis, b1, W2, p,            \
                                               (int)n, f0, f0 == 0);               \
    }

    switch (FC) {
        case 16: RUN_CHUNKED(16); break;
        case 8:  RUN_CHUNKED(8);  break;
        case 4:  RUN_CHUNKED(4);  break;
        case 2:  RUN_CHUNKED(2);  break;
        default: RUN_CHUNKED(1);  break;
    }
#undef RUN_CHUNKED

    k_outinit<<<gridN, 256, 0, stream>>>(dis, p, b2, out, (int)n);
    k_agg2<<<gridE, 256, 0, stream>>>(ei32, ei64, E, ew, dis, p, out, (int)n);
}